// Round 1
// baseline (6416.539 us; speedup 1.0000x reference)
//
#include <hip/hip_runtime.h>
#include <math.h>

#define D64 64
#define ES16 16

__device__ __forceinline__ float sigf(float x){ return 1.0f/(1.0f + __expf(-x)); }
__device__ __forceinline__ float tanhfast(float x){ return 2.0f*sigf(2.0f*x) - 1.0f; }

// ---------------- CSR build ----------------
__global__ void k_count(const int* __restrict__ u, const int* __restrict__ v,
                        int* __restrict__ cnt, int N, int E){
  int e = blockIdx.x*256 + threadIdx.x;
  if(e < E){
    atomicAdd(&cnt[v[e]], 1);
    atomicAdd(&cnt[N + u[e]], 1);
  }
}

__global__ void k_scan1(const int* __restrict__ cnt, int* __restrict__ part, int M){
  __shared__ int sm[256];
  int i = blockIdx.x*256 + threadIdx.x;
  sm[threadIdx.x] = (i < M) ? cnt[i] : 0;
  __syncthreads();
  for(int s = 128; s > 0; s >>= 1){
    if(threadIdx.x < s) sm[threadIdx.x] += sm[threadIdx.x + s];
    __syncthreads();
  }
  if(threadIdx.x == 0) part[blockIdx.x] = sm[0];
}

__global__ void k_scan2(int* __restrict__ part, int nb){
  __shared__ int sm[1024];
  int t = threadIdx.x;
  int orig = (t < nb) ? part[t] : 0;
  sm[t] = orig;
  __syncthreads();
  for(int off = 1; off < 1024; off <<= 1){
    int add = (t >= off) ? sm[t - off] : 0;
    __syncthreads();
    sm[t] += add;
    __syncthreads();
  }
  if(t < nb) part[t] = sm[t] - orig;  // exclusive prefix
}

__global__ void k_scan3(int* __restrict__ cnt, const int* __restrict__ part,
                        int* __restrict__ cur, int M, int total){
  __shared__ int sm[256];
  int t = threadIdx.x;
  int i = blockIdx.x*256 + t;
  int orig = (i < M) ? cnt[i] : 0;
  sm[t] = orig;
  __syncthreads();
  for(int off = 1; off < 256; off <<= 1){
    int add = (t >= off) ? sm[t - off] : 0;
    __syncthreads();
    sm[t] += add;
    __syncthreads();
  }
  if(i < M){
    int excl = part[blockIdx.x] + sm[t] - orig;
    cnt[i] = excl;
    cur[i] = excl;
  }
  if(i == 0) cnt[M] = total;
}

__global__ void k_fill(const int* __restrict__ u, const int* __restrict__ v,
                       int* __restrict__ cur, int* __restrict__ rows, int N, int E){
  int e = blockIdx.x*256 + threadIdx.x;
  if(e < E){
    int p = atomicAdd(&cur[v[e]], 1); rows[p] = e;
    int q = atomicAdd(&cur[N + u[e]], 1); rows[q] = e;
  }
}

// ---------------- round-constant edge-feature sums ----------------
__global__ void k_einout(const float* __restrict__ ev, const int* __restrict__ off,
                         const int* __restrict__ rows,
                         float* __restrict__ Ein, float* __restrict__ Eout, int N){
  int n = (blockIdx.x*blockDim.x + threadIdx.x) >> 6;
  int lane = threadIdx.x & 63;
  if(n >= N) return;
  int t = lane & 15, s = lane >> 4;
  float a = 0.f;
  int p1 = off[n+1];
  for(int p = off[n] + s; p < p1; p += 4) a += ev[rows[p]*ES16 + t];
  a += __shfl_xor(a, 16, 64);
  a += __shfl_xor(a, 32, 64);
  if(lane < 16) Ein[n*ES16 + lane] = a;
  float b = 0.f;
  p1 = off[N+n+1];
  for(int p = off[N+n] + s; p < p1; p += 4) b += ev[rows[p]*ES16 + t];
  b += __shfl_xor(b, 16, 64);
  b += __shfl_xor(b, 32, 64);
  if(lane < 16) Eout[n*ES16 + lane] = b;
}

// ---------------- per-round sparse aggregation (wave per node) ----------------
__global__ void k_aggr(const float* __restrict__ h, const int* __restrict__ off,
                       const int* __restrict__ rows, const int* __restrict__ uidx,
                       const int* __restrict__ vidx,
                       float* __restrict__ Sin, float* __restrict__ Sout, int N){
  int n = (blockIdx.x*blockDim.x + threadIdx.x) >> 6;
  int lane = threadIdx.x & 63;
  if(n >= N) return;
  float s = 0.f;
  int p1 = off[n+1];
  for(int p = off[n]; p < p1; ++p){
    int e = rows[p];
    s += h[uidx[e]*D64 + lane];
  }
  Sin[n*D64 + lane] = s;
  s = 0.f;
  p1 = off[N+n+1];
  for(int p = off[N+n]; p < p1; ++p){
    int e = rows[p];
    s += h[vidx[e]*D64 + lane];
  }
  Sout[n*D64 + lane] = s;
}

// ---------------- node transform: agg = Wef*xf + Wer*xr + deg*biases ----------------
__global__ __launch_bounds__(64) void k3_agg(
    const float* __restrict__ h, const float* __restrict__ Sin,
    const float* __restrict__ Sout, const float* __restrict__ Ein,
    const float* __restrict__ Eout, const int* __restrict__ off,
    const float* __restrict__ Wef, const float* __restrict__ bef,
    const float* __restrict__ Wer, const float* __restrict__ ber,
    float* __restrict__ aggT, int N){
  __shared__ float xT[290][67];
  const int lane = threadIdx.x;
  const int base = blockIdx.x * 64;
  for(int i = 0; i < 64; ++i){
    int n = base + i; if(n >= N) n = N - 1;
    float fi = (float)(off[n+1] - off[n]);
    float fo = (float)(off[N+n+1] - off[N+n]);
    float hv = h[n*D64 + lane];
    xT[lane][i]      = Sin[n*D64 + lane];        // rows 0..63   <-> Wef cols 0..63 (h_u)
    xT[64+lane][i]   = fi * hv;                  // rows 64..127 <-> Wef cols 64..127 (h_v = self)
    xT[144+lane][i]  = fo * hv;                  // rows 144..207<-> Wer cols 0..63 (h_u = self)
    xT[208+lane][i]  = Sout[n*D64 + lane];       // rows 208..271<-> Wer cols 64..127 (h_v)
    if(lane < 16){
      xT[128+lane][i] = Ein[n*ES16 + lane];      // rows 128..143 <-> Wef cols 128..143 (ev)
      xT[272+lane][i] = Eout[n*ES16 + lane];     // rows 272..287 <-> Wer cols 128..143 (ev)
    }
    if(lane == 0){ xT[288][i] = fi; xT[289][i] = fo; }
  }
  __syncthreads();
  const float indeg = xT[288][lane];
  const float outdeg = xT[289][lane];
  const bool valid = (base + lane) < N;
  for(int jt = 0; jt < 16; ++jt){
    float acc[8];
    #pragma unroll
    for(int jj = 0; jj < 8; ++jj){
      int j = jt*8 + jj;
      acc[jj] = indeg*bef[j] + outdeg*ber[j];
    }
    #pragma unroll 4
    for(int k4 = 0; k4 < 36; ++k4){
      float x0 = xT[k4*4+0][lane];
      float x1 = xT[k4*4+1][lane];
      float x2 = xT[k4*4+2][lane];
      float x3 = xT[k4*4+3][lane];
      #pragma unroll
      for(int jj = 0; jj < 8; ++jj){
        int j = jt*8 + jj;
        float4 w = *(const float4*)(Wef + j*144 + k4*4);
        acc[jj] = fmaf(w.x, x0, acc[jj]);
        acc[jj] = fmaf(w.y, x1, acc[jj]);
        acc[jj] = fmaf(w.z, x2, acc[jj]);
        acc[jj] = fmaf(w.w, x3, acc[jj]);
      }
    }
    #pragma unroll 4
    for(int k4 = 0; k4 < 36; ++k4){
      float x0 = xT[144+k4*4+0][lane];
      float x1 = xT[144+k4*4+1][lane];
      float x2 = xT[144+k4*4+2][lane];
      float x3 = xT[144+k4*4+3][lane];
      #pragma unroll
      for(int jj = 0; jj < 8; ++jj){
        int j = jt*8 + jj;
        float4 w = *(const float4*)(Wer + j*144 + k4*4);
        acc[jj] = fmaf(w.x, x0, acc[jj]);
        acc[jj] = fmaf(w.y, x1, acc[jj]);
        acc[jj] = fmaf(w.z, x2, acc[jj]);
        acc[jj] = fmaf(w.w, x3, acc[jj]);
      }
    }
    if(valid){
      #pragma unroll
      for(int jj = 0; jj < 8; ++jj)
        aggT[(size_t)(jt*8+jj)*N + base + lane] = acc[jj];
    }
  }
}

// ---------------- GRU: h' from aggT + h ----------------
__global__ __launch_bounds__(64) void k4_gru(
    const float* __restrict__ hcur, const float* __restrict__ aggT,
    const float* __restrict__ Wih, const float* __restrict__ Whh,
    const float* __restrict__ bih, const float* __restrict__ bhh,
    float* __restrict__ hnext, int N){
  __shared__ float xT[192][67];   // rows 0..127 agg, rows 128..191 h
  __shared__ float ht[64][67];
  const int lane = threadIdx.x;
  const int base = blockIdx.x * 64;
  {
    int n = base + lane; if(n >= N) n = N - 1;
    for(int k = 0; k < 128; ++k) xT[k][lane] = aggT[(size_t)k*N + n];
  }
  for(int i = 0; i < 64; ++i){
    int n = base + i; if(n >= N) n = N - 1;
    xT[128 + lane][i] = hcur[n*D64 + lane];
  }
  __syncthreads();
  for(int qt = 0; qt < 8; ++qt){
    float aR[8], aZ[8], aN[8], aH[8];
    #pragma unroll
    for(int i = 0; i < 8; ++i){
      int q = qt*8 + i;
      aR[i] = bih[q]      + bhh[q];
      aZ[i] = bih[64+q]   + bhh[64+q];
      aN[i] = bih[128+q];
      aH[i] = bhh[128+q];
    }
    #pragma unroll 2
    for(int k4 = 0; k4 < 32; ++k4){
      float x0 = xT[k4*4+0][lane];
      float x1 = xT[k4*4+1][lane];
      float x2 = xT[k4*4+2][lane];
      float x3 = xT[k4*4+3][lane];
      #pragma unroll
      for(int i = 0; i < 8; ++i){
        int q = qt*8 + i;
        float4 wr = *(const float4*)(Wih + q*128       + k4*4);
        float4 wz = *(const float4*)(Wih + (64+q)*128  + k4*4);
        float4 wn = *(const float4*)(Wih + (128+q)*128 + k4*4);
        aR[i] = fmaf(wr.x,x0,fmaf(wr.y,x1,fmaf(wr.z,x2,fmaf(wr.w,x3,aR[i]))));
        aZ[i] = fmaf(wz.x,x0,fmaf(wz.y,x1,fmaf(wz.z,x2,fmaf(wz.w,x3,aZ[i]))));
        aN[i] = fmaf(wn.x,x0,fmaf(wn.y,x1,fmaf(wn.z,x2,fmaf(wn.w,x3,aN[i]))));
      }
    }
    #pragma unroll 2
    for(int k4 = 0; k4 < 16; ++k4){
      float x0 = xT[128+k4*4+0][lane];
      float x1 = xT[128+k4*4+1][lane];
      float x2 = xT[128+k4*4+2][lane];
      float x3 = xT[128+k4*4+3][lane];
      #pragma unroll
      for(int i = 0; i < 8; ++i){
        int q = qt*8 + i;
        float4 wr = *(const float4*)(Whh + q*64       + k4*4);
        float4 wz = *(const float4*)(Whh + (64+q)*64  + k4*4);
        float4 wh = *(const float4*)(Whh + (128+q)*64 + k4*4);
        aR[i] = fmaf(wr.x,x0,fmaf(wr.y,x1,fmaf(wr.z,x2,fmaf(wr.w,x3,aR[i]))));
        aZ[i] = fmaf(wz.x,x0,fmaf(wz.y,x1,fmaf(wz.z,x2,fmaf(wz.w,x3,aZ[i]))));
        aH[i] = fmaf(wh.x,x0,fmaf(wh.y,x1,fmaf(wh.z,x2,fmaf(wh.w,x3,aH[i]))));
      }
    }
    #pragma unroll
    for(int i = 0; i < 8; ++i){
      int q = qt*8 + i;
      float r = sigf(aR[i]);
      float z = sigf(aZ[i]);
      float nn = tanhfast(aN[i] + r*aH[i]);
      float hq = xT[128+q][lane];
      ht[q][lane] = (1.f - z)*nn + z*hq;
    }
  }
  __syncthreads();
  for(int i = 0; i < 64; ++i){
    int n = base + i;
    if(n < N) hnext[n*D64 + lane] = ht[lane][i];
  }
}

// ---------------- gated readout ----------------
__global__ __launch_bounds__(64) void k5_read(
    const float* __restrict__ h, const float* __restrict__ Wfm,
    const float* __restrict__ bfm, const float* __restrict__ Wgm,
    const float* __restrict__ bgm, float* __restrict__ hG, int N){
  __shared__ float xT[64][67];
  const int lane = threadIdx.x;
  const int base = blockIdx.x * 64;
  for(int i = 0; i < 64; ++i){
    int n = base + i; if(n >= N) n = N - 1;
    xT[lane][i] = h[n*D64 + lane];
  }
  __syncthreads();
  const bool valid = (base + lane) < N;
  for(int jt = 0; jt < 16; ++jt){
    float aF[8], aG[8];
    #pragma unroll
    for(int jj = 0; jj < 8; ++jj){
      int j = jt*8 + jj;
      aF[jj] = bfm[j]; aG[jj] = bgm[j];
    }
    #pragma unroll 2
    for(int k4 = 0; k4 < 16; ++k4){
      float x0 = xT[k4*4+0][lane];
      float x1 = xT[k4*4+1][lane];
      float x2 = xT[k4*4+2][lane];
      float x3 = xT[k4*4+3][lane];
      #pragma unroll
      for(int jj = 0; jj < 8; ++jj){
        int j = jt*8 + jj;
        float4 wf = *(const float4*)(Wfm + j*64 + k4*4);
        float4 wg = *(const float4*)(Wgm + j*64 + k4*4);
        aF[jj] = fmaf(wf.x,x0,fmaf(wf.y,x1,fmaf(wf.z,x2,fmaf(wf.w,x3,aF[jj]))));
        aG[jj] = fmaf(wg.x,x0,fmaf(wg.y,x1,fmaf(wg.z,x2,fmaf(wg.w,x3,aG[jj]))));
      }
    }
    #pragma unroll
    for(int jj = 0; jj < 8; ++jj){
      float val = aF[jj] * sigf(aG[jj]);
      if(!valid) val = 0.f;
      #pragma unroll
      for(int o = 32; o > 0; o >>= 1) val += __shfl_xor(val, o, 64);
      if(lane == 0) atomicAdd(&hG[jt*8+jj], val);
    }
  }
}

__global__ void k6_dec(const float* __restrict__ hG, const float* __restrict__ h,
                       const float* __restrict__ Wdec, const float* __restrict__ bdec,
                       const int* __restrict__ tgt, float* __restrict__ out){
  __shared__ float sm[256];
  int t = threadIdx.x;
  float v = 0.f;
  if(t < 128) v = hG[t] * Wdec[t];
  else if(t < 192) v = h[tgt[0]*D64 + (t - 128)] * Wdec[t];
  sm[t] = v;
  __syncthreads();
  for(int s = 128; s > 0; s >>= 1){
    if(t < s) sm[t] += sm[t + s];
    __syncthreads();
  }
  if(t == 0) out[0] = sm[0] + bdec[0];
}

extern "C" void kernel_launch(void* const* d_in, const int* in_sizes, int n_in,
                              void* d_out, int out_size, void* d_ws, size_t ws_size,
                              hipStream_t stream){
  const float* nodev = (const float*)d_in[0];
  const float* ev    = (const float*)d_in[1];
  const float* Wef   = (const float*)d_in[2];
  const float* bef   = (const float*)d_in[3];
  const float* Wer   = (const float*)d_in[4];
  const float* ber   = (const float*)d_in[5];
  const float* Wih   = (const float*)d_in[6];
  const float* Whh   = (const float*)d_in[7];
  const float* bih   = (const float*)d_in[8];
  const float* bhh   = (const float*)d_in[9];
  const float* Wfm   = (const float*)d_in[10];
  const float* bfm   = (const float*)d_in[11];
  const float* Wgm   = (const float*)d_in[12];
  const float* bgm   = (const float*)d_in[13];
  const float* Wdec  = (const float*)d_in[14];
  const float* bdec  = (const float*)d_in[15];
  const int* uidx    = (const int*)d_in[16];
  const int* vidx    = (const int*)d_in[17];
  const int* tgt     = (const int*)d_in[18];

  const int N = in_sizes[0] / 64;
  const int E = in_sizes[16];
  const int R = in_sizes[2] / (128*144);

  char* w = (char*)d_ws;
  auto alloc = [&](size_t bytes) -> void* {
    void* p = (void*)w;
    w += (bytes + 255) & ~(size_t)255;
    return p;
  };
  int* off    = (int*)alloc(((size_t)2*N + 1) * 4);
  int* cur    = (int*)alloc((size_t)2*N * 4);
  int* rows   = (int*)alloc((size_t)2*E * 4);
  int* part   = (int*)alloc(4096 * 4);
  float* Ein  = (float*)alloc((size_t)N*16*4);
  float* Eout = (float*)alloc((size_t)N*16*4);
  float* Sin  = (float*)alloc((size_t)N*64*4);
  float* Sout = (float*)alloc((size_t)N*64*4);
  float* hA   = (float*)alloc((size_t)N*64*4);
  float* hB   = (float*)alloc((size_t)N*64*4);
  float* aggT = (float*)alloc((size_t)128*N*4);
  float* hG   = (float*)alloc(512);

  hipMemsetAsync(off, 0, ((size_t)2*N+1)*4, stream);
  hipMemsetAsync(hG, 0, 512, stream);

  int eb = (E + 255)/256;
  k_count<<<eb, 256, 0, stream>>>(uidx, vidx, off, N, E);
  int M = 2*N;
  int nb = (M + 255)/256;
  k_scan1<<<nb, 256, 0, stream>>>(off, part, M);
  k_scan2<<<1, 1024, 0, stream>>>(part, nb);
  k_scan3<<<nb, 256, 0, stream>>>(off, part, cur, M, 2*E);
  k_fill<<<eb, 256, 0, stream>>>(uidx, vidx, cur, rows, N, E);
  int wb = (N + 3)/4;
  k_einout<<<wb, 256, 0, stream>>>(ev, off, rows, Ein, Eout, N);

  int nT = (N + 63)/64;
  const float* hcur = nodev;
  float* bufs[2] = {hA, hB};
  for(int r = 0; r < R; ++r){
    k_aggr<<<wb, 256, 0, stream>>>(hcur, off, rows, uidx, vidx, Sin, Sout, N);
    k3_agg<<<nT, 64, 0, stream>>>(hcur, Sin, Sout, Ein, Eout, off,
                                  Wef + (size_t)r*128*144, bef + r*128,
                                  Wer + (size_t)r*128*144, ber + r*128,
                                  aggT, N);
    float* hn = bufs[r & 1];
    k4_gru<<<nT, 64, 0, stream>>>(hcur, aggT,
                                  Wih + (size_t)r*192*128, Whh + (size_t)r*192*64,
                                  bih + r*192, bhh + r*192, hn, N);
    hcur = hn;
  }
  k5_read<<<nT, 64, 0, stream>>>(hcur, Wfm, bfm, Wgm, bgm, hG, N);
  k6_dec<<<1, 256, 0, stream>>>(hG, hcur, Wdec, bdec, tgt, (float*)d_out);
}

// Round 2
// 3120.244 us; speedup vs baseline: 2.0564x; 2.0564x over previous
//
#include <hip/hip_runtime.h>
#include <math.h>

#define D64 64
#define ES16 16

__device__ __forceinline__ float sigf(float x){ return 1.0f/(1.0f + __expf(-x)); }
__device__ __forceinline__ float tanhfast(float x){ return 2.0f*sigf(2.0f*x) - 1.0f; }

// ---------------- CSR build ----------------
__global__ void k_count(const int* __restrict__ u, const int* __restrict__ v,
                        int* __restrict__ cnt, int N, int E){
  int e = blockIdx.x*256 + threadIdx.x;
  if(e < E){
    atomicAdd(&cnt[v[e]], 1);
    atomicAdd(&cnt[N + u[e]], 1);
  }
}

__global__ void k_scan1(const int* __restrict__ cnt, int* __restrict__ part, int M){
  __shared__ int sm[256];
  int i = blockIdx.x*256 + threadIdx.x;
  sm[threadIdx.x] = (i < M) ? cnt[i] : 0;
  __syncthreads();
  for(int s = 128; s > 0; s >>= 1){
    if(threadIdx.x < s) sm[threadIdx.x] += sm[threadIdx.x + s];
    __syncthreads();
  }
  if(threadIdx.x == 0) part[blockIdx.x] = sm[0];
}

__global__ void k_scan2(int* __restrict__ part, int nb){
  __shared__ int sm[1024];
  int t = threadIdx.x;
  int orig = (t < nb) ? part[t] : 0;
  sm[t] = orig;
  __syncthreads();
  for(int off = 1; off < 1024; off <<= 1){
    int add = (t >= off) ? sm[t - off] : 0;
    __syncthreads();
    sm[t] += add;
    __syncthreads();
  }
  if(t < nb) part[t] = sm[t] - orig;  // exclusive prefix
}

__global__ void k_scan3(int* __restrict__ cnt, const int* __restrict__ part,
                        int* __restrict__ cur, int M, int total){
  __shared__ int sm[256];
  int t = threadIdx.x;
  int i = blockIdx.x*256 + t;
  int orig = (i < M) ? cnt[i] : 0;
  sm[t] = orig;
  __syncthreads();
  for(int off = 1; off < 256; off <<= 1){
    int add = (t >= off) ? sm[t - off] : 0;
    __syncthreads();
    sm[t] += add;
    __syncthreads();
  }
  if(i < M){
    int excl = part[blockIdx.x] + sm[t] - orig;
    cnt[i] = excl;
    cur[i] = excl;
  }
  if(i == 0) cnt[M] = total;
}

__global__ void k_fill(const int* __restrict__ u, const int* __restrict__ v,
                       int* __restrict__ cur, int* __restrict__ rows, int N, int E){
  int e = blockIdx.x*256 + threadIdx.x;
  if(e < E){
    int p = atomicAdd(&cur[v[e]], 1); rows[p] = e;
    int q = atomicAdd(&cur[N + u[e]], 1); rows[q] = e;
  }
}

// ---------------- round-constant edge-feature sums ----------------
__global__ void k_einout(const float* __restrict__ ev, const int* __restrict__ off,
                         const int* __restrict__ rows,
                         float* __restrict__ Ein, float* __restrict__ Eout, int N){
  int n = (blockIdx.x*blockDim.x + threadIdx.x) >> 6;
  int lane = threadIdx.x & 63;
  if(n >= N) return;
  int t = lane & 15, s = lane >> 4;
  float a = 0.f;
  int p1 = off[n+1];
  for(int p = off[n] + s; p < p1; p += 4) a += ev[rows[p]*ES16 + t];
  a += __shfl_xor(a, 16, 64);
  a += __shfl_xor(a, 32, 64);
  if(lane < 16) Ein[n*ES16 + lane] = a;
  float b = 0.f;
  p1 = off[N+n+1];
  for(int p = off[N+n] + s; p < p1; p += 4) b += ev[rows[p]*ES16 + t];
  b += __shfl_xor(b, 16, 64);
  b += __shfl_xor(b, 32, 64);
  if(lane < 16) Eout[n*ES16 + lane] = b;
}

// ---------------- per-round sparse aggregation (wave per node) ----------------
__global__ void k_aggr(const float* __restrict__ h, const int* __restrict__ off,
                       const int* __restrict__ rows, const int* __restrict__ uidx,
                       const int* __restrict__ vidx,
                       float* __restrict__ Sin, float* __restrict__ Sout, int N){
  int n = (blockIdx.x*blockDim.x + threadIdx.x) >> 6;
  int lane = threadIdx.x & 63;
  if(n >= N) return;
  float s = 0.f;
  int p1 = off[n+1];
  for(int p = off[n]; p < p1; ++p){
    int e = rows[p];
    s += h[uidx[e]*D64 + lane];
  }
  Sin[n*D64 + lane] = s;
  s = 0.f;
  p1 = off[N+n+1];
  for(int p = off[N+n]; p < p1; ++p){
    int e = rows[p];
    s += h[vidx[e]*D64 + lane];
  }
  Sout[n*D64 + lane] = s;
}

// ---------------- node transform: agg = Wef*xf + Wer*xr + deg*biases ----------------
// 512 threads = 8 waves per 64-node tile; wave wv computes jt = {wv, wv+8}.
// LDS rows: 0..63 Sin | 64..127 h | 128..143 Ein | 144..207 Sout | 208..223 Eout
__global__ __launch_bounds__(512) void k3_agg(
    const float* __restrict__ h, const float* __restrict__ Sin,
    const float* __restrict__ Sout, const float* __restrict__ Ein,
    const float* __restrict__ Eout, const int* __restrict__ off,
    const float* __restrict__ Wef, const float* __restrict__ bef,
    const float* __restrict__ Wer, const float* __restrict__ ber,
    float* __restrict__ aggT, int N){
  __shared__ float xT[224][67];
  __shared__ float fdeg[2][68];
  const int lane = threadIdx.x & 63;
  const int wv   = threadIdx.x >> 6;
  const int base = blockIdx.x * 64;
  for(int ii = 0; ii < 8; ++ii){
    int i = wv*8 + ii;
    int n = base + i; if(n >= N) n = N - 1;
    xT[lane][i]       = Sin[n*D64 + lane];
    xT[64+lane][i]    = h[n*D64 + lane];
    xT[144+lane][i]   = Sout[n*D64 + lane];
    if(lane < 16){
      xT[128+lane][i] = Ein[n*ES16 + lane];
      xT[208+lane][i] = Eout[n*ES16 + lane];
    }
    if(lane == 0){
      fdeg[0][i] = (float)(off[n+1] - off[n]);
      fdeg[1][i] = (float)(off[N+n+1] - off[N+n]);
    }
  }
  __syncthreads();
  const float fi = fdeg[0][lane];
  const float fo = fdeg[1][lane];
  const bool valid = (base + lane) < N;
  for(int t = 0; t < 2; ++t){
    const int jt = wv + t*8;
    float acc[8];
    #pragma unroll
    for(int jj = 0; jj < 8; ++jj){
      int j = jt*8 + jj;
      acc[jj] = fi*bef[j] + fo*ber[j];
    }
    // Sin block: Wef cols 0..63
    #pragma unroll 4
    for(int k4 = 0; k4 < 16; ++k4){
      float x0 = xT[k4*4+0][lane];
      float x1 = xT[k4*4+1][lane];
      float x2 = xT[k4*4+2][lane];
      float x3 = xT[k4*4+3][lane];
      #pragma unroll
      for(int jj = 0; jj < 8; ++jj){
        float4 w = *(const float4*)(Wef + (jt*8+jj)*144 + k4*4);
        acc[jj] = fmaf(w.x,x0,fmaf(w.y,x1,fmaf(w.z,x2,fmaf(w.w,x3,acc[jj]))));
      }
    }
    // h block: Wef cols 64..127 (×fi) and Wer cols 0..63 (×fo) share LDS reads
    #pragma unroll 2
    for(int k4 = 0; k4 < 16; ++k4){
      float h0 = xT[64+k4*4+0][lane];
      float h1 = xT[64+k4*4+1][lane];
      float h2 = xT[64+k4*4+2][lane];
      float h3 = xT[64+k4*4+3][lane];
      float f0 = fi*h0, f1 = fi*h1, f2 = fi*h2, f3 = fi*h3;
      float r0 = fo*h0, r1 = fo*h1, r2 = fo*h2, r3 = fo*h3;
      #pragma unroll
      for(int jj = 0; jj < 8; ++jj){
        int j = jt*8 + jj;
        float4 wf = *(const float4*)(Wef + j*144 + 64 + k4*4);
        float4 wr = *(const float4*)(Wer + j*144 + k4*4);
        acc[jj] = fmaf(wf.x,f0,fmaf(wf.y,f1,fmaf(wf.z,f2,fmaf(wf.w,f3,acc[jj]))));
        acc[jj] = fmaf(wr.x,r0,fmaf(wr.y,r1,fmaf(wr.z,r2,fmaf(wr.w,r3,acc[jj]))));
      }
    }
    // Ein block: Wef cols 128..143
    #pragma unroll
    for(int k4 = 0; k4 < 4; ++k4){
      float x0 = xT[128+k4*4+0][lane];
      float x1 = xT[128+k4*4+1][lane];
      float x2 = xT[128+k4*4+2][lane];
      float x3 = xT[128+k4*4+3][lane];
      #pragma unroll
      for(int jj = 0; jj < 8; ++jj){
        float4 w = *(const float4*)(Wef + (jt*8+jj)*144 + 128 + k4*4);
        acc[jj] = fmaf(w.x,x0,fmaf(w.y,x1,fmaf(w.z,x2,fmaf(w.w,x3,acc[jj]))));
      }
    }
    // Sout block: Wer cols 64..127
    #pragma unroll 4
    for(int k4 = 0; k4 < 16; ++k4){
      float x0 = xT[144+k4*4+0][lane];
      float x1 = xT[144+k4*4+1][lane];
      float x2 = xT[144+k4*4+2][lane];
      float x3 = xT[144+k4*4+3][lane];
      #pragma unroll
      for(int jj = 0; jj < 8; ++jj){
        float4 w = *(const float4*)(Wer + (jt*8+jj)*144 + 64 + k4*4);
        acc[jj] = fmaf(w.x,x0,fmaf(w.y,x1,fmaf(w.z,x2,fmaf(w.w,x3,acc[jj]))));
      }
    }
    // Eout block: Wer cols 128..143
    #pragma unroll
    for(int k4 = 0; k4 < 4; ++k4){
      float x0 = xT[208+k4*4+0][lane];
      float x1 = xT[208+k4*4+1][lane];
      float x2 = xT[208+k4*4+2][lane];
      float x3 = xT[208+k4*4+3][lane];
      #pragma unroll
      for(int jj = 0; jj < 8; ++jj){
        float4 w = *(const float4*)(Wer + (jt*8+jj)*144 + 128 + k4*4);
        acc[jj] = fmaf(w.x,x0,fmaf(w.y,x1,fmaf(w.z,x2,fmaf(w.w,x3,acc[jj]))));
      }
    }
    if(valid){
      #pragma unroll
      for(int jj = 0; jj < 8; ++jj)
        aggT[(size_t)(jt*8+jj)*N + base + lane] = acc[jj];
    }
  }
}

// ---------------- GRU: h' from aggT + h ----------------
// 512 threads = 8 waves per 64-node tile; wave wv computes qt = wv.
__global__ __launch_bounds__(512) void k4_gru(
    const float* __restrict__ hcur, const float* __restrict__ aggT,
    const float* __restrict__ Wih, const float* __restrict__ Whh,
    const float* __restrict__ bih, const float* __restrict__ bhh,
    float* __restrict__ hnext, int N){
  __shared__ float xT[192][67];   // rows 0..127 agg, rows 128..191 h
  __shared__ float ht[64][67];
  const int lane = threadIdx.x & 63;
  const int wv   = threadIdx.x >> 6;
  const int base = blockIdx.x * 64;
  {
    int n = base + lane; if(n >= N) n = N - 1;
    for(int kk = 0; kk < 16; ++kk){
      int k = wv*16 + kk;
      xT[k][lane] = aggT[(size_t)k*N + n];
    }
  }
  for(int ii = 0; ii < 8; ++ii){
    int i = wv*8 + ii;
    int n = base + i; if(n >= N) n = N - 1;
    xT[128 + lane][i] = hcur[n*D64 + lane];
  }
  __syncthreads();
  {
    const int qt = wv;
    float aR[8], aZ[8], aN[8], aH[8];
    #pragma unroll
    for(int i = 0; i < 8; ++i){
      int q = qt*8 + i;
      aR[i] = bih[q]      + bhh[q];
      aZ[i] = bih[64+q]   + bhh[64+q];
      aN[i] = bih[128+q];
      aH[i] = bhh[128+q];
    }
    #pragma unroll 2
    for(int k4 = 0; k4 < 32; ++k4){
      float x0 = xT[k4*4+0][lane];
      float x1 = xT[k4*4+1][lane];
      float x2 = xT[k4*4+2][lane];
      float x3 = xT[k4*4+3][lane];
      #pragma unroll
      for(int i = 0; i < 8; ++i){
        int q = qt*8 + i;
        float4 wr = *(const float4*)(Wih + q*128       + k4*4);
        float4 wz = *(const float4*)(Wih + (64+q)*128  + k4*4);
        float4 wn = *(const float4*)(Wih + (128+q)*128 + k4*4);
        aR[i] = fmaf(wr.x,x0,fmaf(wr.y,x1,fmaf(wr.z,x2,fmaf(wr.w,x3,aR[i]))));
        aZ[i] = fmaf(wz.x,x0,fmaf(wz.y,x1,fmaf(wz.z,x2,fmaf(wz.w,x3,aZ[i]))));
        aN[i] = fmaf(wn.x,x0,fmaf(wn.y,x1,fmaf(wn.z,x2,fmaf(wn.w,x3,aN[i]))));
      }
    }
    #pragma unroll 2
    for(int k4 = 0; k4 < 16; ++k4){
      float x0 = xT[128+k4*4+0][lane];
      float x1 = xT[128+k4*4+1][lane];
      float x2 = xT[128+k4*4+2][lane];
      float x3 = xT[128+k4*4+3][lane];
      #pragma unroll
      for(int i = 0; i < 8; ++i){
        int q = qt*8 + i;
        float4 wr = *(const float4*)(Whh + q*64       + k4*4);
        float4 wz = *(const float4*)(Whh + (64+q)*64  + k4*4);
        float4 wh = *(const float4*)(Whh + (128+q)*64 + k4*4);
        aR[i] = fmaf(wr.x,x0,fmaf(wr.y,x1,fmaf(wr.z,x2,fmaf(wr.w,x3,aR[i]))));
        aZ[i] = fmaf(wz.x,x0,fmaf(wz.y,x1,fmaf(wz.z,x2,fmaf(wz.w,x3,aZ[i]))));
        aH[i] = fmaf(wh.x,x0,fmaf(wh.y,x1,fmaf(wh.z,x2,fmaf(wh.w,x3,aH[i]))));
      }
    }
    #pragma unroll
    for(int i = 0; i < 8; ++i){
      int q = qt*8 + i;
      float r = sigf(aR[i]);
      float z = sigf(aZ[i]);
      float nn = tanhfast(aN[i] + r*aH[i]);
      float hq = xT[128+q][lane];
      ht[q][lane] = (1.f - z)*nn + z*hq;
    }
  }
  __syncthreads();
  for(int ii = 0; ii < 8; ++ii){
    int i = wv*8 + ii;
    int n = base + i;
    if(n < N) hnext[n*D64 + lane] = ht[lane][i];
  }
}

// ---------------- gated readout ----------------
__global__ __launch_bounds__(512) void k5_read(
    const float* __restrict__ h, const float* __restrict__ Wfm,
    const float* __restrict__ bfm, const float* __restrict__ Wgm,
    const float* __restrict__ bgm, float* __restrict__ hG, int N){
  __shared__ float xT[64][67];
  const int lane = threadIdx.x & 63;
  const int wv   = threadIdx.x >> 6;
  const int base = blockIdx.x * 64;
  for(int ii = 0; ii < 8; ++ii){
    int i = wv*8 + ii;
    int n = base + i; if(n >= N) n = N - 1;
    xT[lane][i] = h[n*D64 + lane];
  }
  __syncthreads();
  const bool valid = (base + lane) < N;
  for(int t = 0; t < 2; ++t){
    const int jt = wv + t*8;
    float aF[8], aG[8];
    #pragma unroll
    for(int jj = 0; jj < 8; ++jj){
      int j = jt*8 + jj;
      aF[jj] = bfm[j]; aG[jj] = bgm[j];
    }
    #pragma unroll 2
    for(int k4 = 0; k4 < 16; ++k4){
      float x0 = xT[k4*4+0][lane];
      float x1 = xT[k4*4+1][lane];
      float x2 = xT[k4*4+2][lane];
      float x3 = xT[k4*4+3][lane];
      #pragma unroll
      for(int jj = 0; jj < 8; ++jj){
        int j = jt*8 + jj;
        float4 wf = *(const float4*)(Wfm + j*64 + k4*4);
        float4 wg = *(const float4*)(Wgm + j*64 + k4*4);
        aF[jj] = fmaf(wf.x,x0,fmaf(wf.y,x1,fmaf(wf.z,x2,fmaf(wf.w,x3,aF[jj]))));
        aG[jj] = fmaf(wg.x,x0,fmaf(wg.y,x1,fmaf(wg.z,x2,fmaf(wg.w,x3,aG[jj]))));
      }
    }
    #pragma unroll
    for(int jj = 0; jj < 8; ++jj){
      float val = aF[jj] * sigf(aG[jj]);
      if(!valid) val = 0.f;
      #pragma unroll
      for(int o = 32; o > 0; o >>= 1) val += __shfl_xor(val, o, 64);
      if(lane == 0) atomicAdd(&hG[jt*8+jj], val);
    }
  }
}

__global__ void k6_dec(const float* __restrict__ hG, const float* __restrict__ h,
                       const float* __restrict__ Wdec, const float* __restrict__ bdec,
                       const int* __restrict__ tgt, float* __restrict__ out){
  __shared__ float sm[256];
  int t = threadIdx.x;
  float v = 0.f;
  if(t < 128) v = hG[t] * Wdec[t];
  else if(t < 192) v = h[tgt[0]*D64 + (t - 128)] * Wdec[t];
  sm[t] = v;
  __syncthreads();
  for(int s = 128; s > 0; s >>= 1){
    if(t < s) sm[t] += sm[t + s];
    __syncthreads();
  }
  if(t == 0) out[0] = sm[0] + bdec[0];
}

extern "C" void kernel_launch(void* const* d_in, const int* in_sizes, int n_in,
                              void* d_out, int out_size, void* d_ws, size_t ws_size,
                              hipStream_t stream){
  const float* nodev = (const float*)d_in[0];
  const float* ev    = (const float*)d_in[1];
  const float* Wef   = (const float*)d_in[2];
  const float* bef   = (const float*)d_in[3];
  const float* Wer   = (const float*)d_in[4];
  const float* ber   = (const float*)d_in[5];
  const float* Wih   = (const float*)d_in[6];
  const float* Whh   = (const float*)d_in[7];
  const float* bih   = (const float*)d_in[8];
  const float* bhh   = (const float*)d_in[9];
  const float* Wfm   = (const float*)d_in[10];
  const float* bfm   = (const float*)d_in[11];
  const float* Wgm   = (const float*)d_in[12];
  const float* bgm   = (const float*)d_in[13];
  const float* Wdec  = (const float*)d_in[14];
  const float* bdec  = (const float*)d_in[15];
  const int* uidx    = (const int*)d_in[16];
  const int* vidx    = (const int*)d_in[17];
  const int* tgt     = (const int*)d_in[18];

  const int N = in_sizes[0] / 64;
  const int E = in_sizes[16];
  const int R = in_sizes[2] / (128*144);

  char* w = (char*)d_ws;
  auto alloc = [&](size_t bytes) -> void* {
    void* p = (void*)w;
    w += (bytes + 255) & ~(size_t)255;
    return p;
  };
  int* off    = (int*)alloc(((size_t)2*N + 1) * 4);
  int* cur    = (int*)alloc((size_t)2*N * 4);
  int* rows   = (int*)alloc((size_t)2*E * 4);
  int* part   = (int*)alloc(4096 * 4);
  float* Ein  = (float*)alloc((size_t)N*16*4);
  float* Eout = (float*)alloc((size_t)N*16*4);
  float* Sin  = (float*)alloc((size_t)N*64*4);
  float* Sout = (float*)alloc((size_t)N*64*4);
  float* hA   = (float*)alloc((size_t)N*64*4);
  float* hB   = (float*)alloc((size_t)N*64*4);
  float* aggT = (float*)alloc((size_t)128*N*4);
  float* hG   = (float*)alloc(512);

  hipMemsetAsync(off, 0, ((size_t)2*N+1)*4, stream);
  hipMemsetAsync(hG, 0, 512, stream);

  int eb = (E + 255)/256;
  k_count<<<eb, 256, 0, stream>>>(uidx, vidx, off, N, E);
  int M = 2*N;
  int nb = (M + 255)/256;
  k_scan1<<<nb, 256, 0, stream>>>(off, part, M);
  k_scan2<<<1, 1024, 0, stream>>>(part, nb);
  k_scan3<<<nb, 256, 0, stream>>>(off, part, cur, M, 2*E);
  k_fill<<<eb, 256, 0, stream>>>(uidx, vidx, cur, rows, N, E);
  int wb = (N + 3)/4;
  k_einout<<<wb, 256, 0, stream>>>(ev, off, rows, Ein, Eout, N);

  int nT = (N + 63)/64;
  const float* hcur = nodev;
  float* bufs[2] = {hA, hB};
  for(int r = 0; r < R; ++r){
    k_aggr<<<wb, 256, 0, stream>>>(hcur, off, rows, uidx, vidx, Sin, Sout, N);
    k3_agg<<<nT, 512, 0, stream>>>(hcur, Sin, Sout, Ein, Eout, off,
                                   Wef + (size_t)r*128*144, bef + r*128,
                                   Wer + (size_t)r*128*144, ber + r*128,
                                   aggT, N);
    float* hn = bufs[r & 1];
    k4_gru<<<nT, 512, 0, stream>>>(hcur, aggT,
                                   Wih + (size_t)r*192*128, Whh + (size_t)r*192*64,
                                   bih + r*192, bhh + r*192, hn, N);
    hcur = hn;
  }
  k5_read<<<nT, 512, 0, stream>>>(hcur, Wfm, bfm, Wgm, bgm, hG, N);
  k6_dec<<<1, 256, 0, stream>>>(hG, hcur, Wdec, bdec, tgt, (float*)d_out);
}